// Round 21
// baseline (104.398 us; speedup 1.0000x reference)
//
#include <hip/hip_runtime.h>
#include <math.h>

#define N_ATOMS  50000
#define N_NBRS   32
#define N_GAUSS  25
#define RCUT     5.0f
#define TT       88        // nearest-table nodes, spacing RCUT/87 (fits 64KB LDS)
#define TROWS    32
#define NTB      3         // ceil(88/32) table-build blocks
#define MAXZ     100
#define NT32     1563      // ceil(50000/32) 32-atom chunks
#define PBLOCKS  512       // persistent fused blocks (target 2 per CU)
#define NPAIR    (N_ATOMS * N_NBRS)        // 1,600,000
#define PKPAD    (NT32 * 1024)             // 1,600,512 (padded)
#define PKB      782                       // pk-precompute blocks (2048 pairs each)
#define PI_F     3.14159265358979323846f

typedef unsigned int   uint_t;
typedef unsigned short ushort_t;
typedef _Float16 f16;
typedef f16   f16x2 __attribute__((ext_vector_type(2)));
typedef f16   f16x4 __attribute__((ext_vector_type(4)));
typedef f16   f16x8 __attribute__((ext_vector_type(8)));
typedef float f32x4 __attribute__((ext_vector_type(4)));

// fast shifted softplus: max(x,0) + log(0.5 + 0.5*exp(-|x|))
__device__ __forceinline__ float ssp(float x) {
  return fmaxf(x, 0.0f) + __logf(fmaf(0.5f, __expf(-fabsf(x)), 0.5f));
}
__device__ __forceinline__ f16x2 bch(uint_t u) {
  return __builtin_bit_cast(f16x2, u);
}
__device__ __forceinline__ uint_t hcb(f16x2 v) {
  return __builtin_bit_cast(uint_t, v);
}
// swizzled element offset into a [16][128] f16 LDS tile
__device__ __forceinline__ int swz(int m, int e) {
  return m * 128 + ((((e >> 3) ^ m) & 15) << 3) + (e & 7);
}

// ---- prep: [0,NTB) table; [NTB,NTB+64) transposes+ytab; [NTB+64,...) pair codes
__global__ void __launch_bounds__(256, 2)
prep_all_kernel(const float* __restrict__ fw1,
                const float* __restrict__ fb1,
                const float* __restrict__ fw2,
                const float* __restrict__ fb2,
                const float* __restrict__ w1,
                const float* __restrict__ w2,
                const float* __restrict__ mw1,
                const float* __restrict__ embed,
                const float* __restrict__ in2f,
                const float* __restrict__ dR,
                const int* __restrict__ nbr,
                const int* __restrict__ Z,
                const float* __restrict__ mb2,
                f16* __restrict__ tabh,
                f16* __restrict__ ytab,
                f16* __restrict__ w1ht,
                f16* __restrict__ w2ht,
                f16* __restrict__ mw1ht,
                uint_t* __restrict__ pkAll,
                float* __restrict__ out) {
  const int tid = threadIdx.x;
  const int bid = blockIdx.x;
  if (bid == 0 && tid == 0) {
    out[0] = 20.0f * (float)N_ATOMS * mb2[0];   // seed with bias term; fused adds the rest
  }

  __shared__ float sW2[128 * 128];       // 64 KB
  __shared__ float sH[TROWS][128];       // 16 KB

  if (bid >= NTB + 64) {
    // ---- pair-code precompute: pk = i0 | (Z[nbr] << 8) ----
    const int base = (bid - NTB - 64) * 2048;
    #pragma unroll
    for (int t0 = 0; t0 < 8; ++t0) {
      const int idx = base + t0 * 256 + tid;
      if (idx < PKPAD) {
        uint_t pk = 0;
        if (idx < NPAIR) {
          const float r = dR[idx];
          const int  nb = nbr[idx];
          int i0 = (int)(r * (87.0f / RCUT) + 0.5f);
          i0 = min(i0, 87);
          pk = (uint_t)i0 | ((uint_t)Z[nb] << 8);
        }
        pkAll[idx] = pk;
      }
    }
    return;
  }

  if (bid < NTB) {
    const int i0 = bid * TROWS;
    #pragma unroll
    for (int t = 0; t < 16; ++t) {
      const int e = tid + t * 256;
      ((float4*)sW2)[e] = ((const float4*)fw2)[e];
    }
    {
      const int f  = tid & 127;
      const int rh = (tid >> 7) * (TROWS / 2);
      const float delta = RCUT / (float)(N_GAUSS - 1);
      const float coeff = -0.5f / (delta * delta);
      const float b1v = fb1[f];
      for (int j = 0; j < TROWS / 2; ++j) {
        const float r = (float)(i0 + rh + j) * (RCUT / 87.0f);
        float h = b1v;
        #pragma unroll
        for (int g = 0; g < N_GAUSS; ++g) {
          const float d = r - (float)g * delta;
          h = fmaf(__expf(coeff * d * d), fw1[g * 128 + f], h);
        }
        sH[rh + j][f] = ssp(h);
      }
    }
    __syncthreads();
    {
      const int c0 = (tid & 31) * 4;
      const int rg = (tid >> 5) * 4;
      f32x4 acc[4];
      const float4 bv = *(const float4*)&fb2[c0];
      #pragma unroll
      for (int j = 0; j < 4; ++j) acc[j] = (f32x4){bv.x, bv.y, bv.z, bv.w};
      for (int k = 0; k < 128; ++k) {
        const float4 wv = *(const float4*)&sW2[k * 128 + c0];
        #pragma unroll
        for (int j = 0; j < 4; ++j) {
          const float hv = sH[rg + j][k];
          acc[j][0] = fmaf(hv, wv.x, acc[j][0]);
          acc[j][1] = fmaf(hv, wv.y, acc[j][1]);
          acc[j][2] = fmaf(hv, wv.z, acc[j][2]);
          acc[j][3] = fmaf(hv, wv.w, acc[j][3]);
        }
      }
      #pragma unroll
      for (int j = 0; j < 4; ++j) {
        const int i = i0 + rg + j;
        if (i < TT) {
          const float r = (float)i * (RCUT / 87.0f);
          const float fc = (r < RCUT) ? 0.5f * (__cosf(r * PI_F / RCUT) + 1.0f) : 0.0f;
          f16x4 o;
          #pragma unroll
          for (int c = 0; c < 4; ++c) o[c] = (f16)(acc[j][c] * fc);
          *(f16x4*)&tabh[i * 128 + c0] = o;
        }
      }
    }
  } else {
    const int cc = (bid - NTB) * 2 + (tid >> 7);
    const int i  = tid & 127;
    w1ht[cc * 128 + i] = (f16)w1[i * 128 + cc];
    w2ht[cc * 128 + i] = (f16)w2[i * 128 + cc];
    if (cc < 64) mw1ht[cc * 128 + i] = (f16)mw1[i * 64 + cc];
    float* xs = &sH[0][0] + (tid >> 7) * 128;
    xs[i] = (cc < MAXZ) ? embed[cc * 128 + i] : 0.0f;
    __syncthreads();
    if (cc < MAXZ) {
      float acc = 0.0f;
      for (int j = 0; j < 128; j += 4) {
        const float4 xv = *reinterpret_cast<const float4*>(&xs[j]);
        acc = fmaf(xv.x, in2f[(j + 0) * 128 + i], acc);
        acc = fmaf(xv.y, in2f[(j + 1) * 128 + i], acc);
        acc = fmaf(xv.z, in2f[(j + 2) * 128 + i], acc);
        acc = fmaf(xv.w, in2f[(j + 3) * 128 + i], acc);
      }
      ytab[cc * 128 + i] = (f16)acc;
    }
  }
}

// ---- fused kernel: same-wave cross-chunk pipeline; LDS < 64 KB so HW can
//      co-schedule 2 blocks/CU (standard-LDS mode). ytab read from global (L1).
__global__ void __launch_bounds__(512, 4)
fused_kernel(const uint_t* __restrict__ pkAll,
             const int* __restrict__ Z,
             const float* __restrict__ embed,
             const f16* __restrict__ tabh,
             const f16* __restrict__ ytab,
             const f16* __restrict__ w1ht, const float* __restrict__ b1,
             const f16* __restrict__ w2ht, const float* __restrict__ b2,
             const f16* __restrict__ mw1ht, const float* __restrict__ mb1,
             const float* __restrict__ mw2,
             float* __restrict__ out) {
  const int tid = threadIdx.x;
  const int w   = tid >> 6;         // wave 0..7
  const int l   = tid & 63;
  const int q   = l >> 4;           // quarter
  const int cq  = l & 15;
  const int bid = blockIdx.x;

  __shared__ __align__(16) f16    sW[TT * 128];      // 22.5 KB nearest table
  __shared__ __align__(16) uint_t s_pk[2][1024];     // 8 KB pair codes (dbuf)
  __shared__ __align__(16) f16    aggB[2][32 * 128]; // 16 KB agg (dbuf)
  __shared__ __align__(16) f16    sB[32 * 128];      // 8 KB h1
  __shared__ __align__(16) f16    sX[32 * 128];      // 8 KB xnew
  __shared__ int   sZb[2][32];
  __shared__ float sRed[8];
  // total ~63.8 KB < 64 KB

  for (int e = tid; e < TT * 16; e += 512) ((uint4*)sW)[e] = ((const uint4*)tabh)[e];

  // dense role indices
  const int g   = w >> 2;           // 16-atom tile within chunk
  const int wvg = w & 3;
  const int rc  = cq;
  const int qk  = q;
  f16x8 bw1[2][4], bw2[2][4], bwm[4];
  float bb1[2], bb2[2];
  #pragma unroll
  for (int t = 0; t < 2; ++t) {
    const int c = wvg * 32 + t * 16 + rc;
    bb1[t] = b1[c];
    bb2[t] = b2[c];
    #pragma unroll
    for (int k0i = 0; k0i < 4; ++k0i) {
      bw1[t][k0i] = *(const f16x8*)&w1ht[c * 128 + k0i * 32 + qk * 8];
      bw2[t][k0i] = *(const f16x8*)&w2ht[c * 128 + k0i * 32 + qk * 8];
    }
  }
  const int c1 = wvg * 16 + rc;
  #pragma unroll
  for (int k0i = 0; k0i < 4; ++k0i)
    bwm[k0i] = *(const f16x8*)&mw1ht[c1 * 128 + k0i * 32 + qk * 8];
  const float bm = mb1[c1];
  const float cm = mw2[c1];

  // cfconv role indices
  const int m = w * 4 + q;          // atom within 32-chunk
  const char* wb = (const char*)sW   + cq * 16;   // LDS table base
  const char* yb = (const char*)ytab + cq * 16;   // GLOBAL ytab base (L1-resident)

  const int myChunks = (NT32 - 1 - bid) / PBLOCKS + 1;
  float vsum = 0.0f;

  f16x2 acc[4];
  uint4 twA[4], ytA[4], twB[4], ytB[4];

#define STAGE(bb, cc) { \
    const uint2 v = *(const uint2*)&pkAll[(cc) * 1024 + tid * 2]; \
    *(uint2*)&s_pk[bb][tid * 2] = v; \
    if (tid < 32) sZb[bb][tid] = ((cc) * 32 + tid < N_ATOMS) ? Z[(cc) * 32 + tid] : 0; }

#define IG(BK, bb, gi) { \
    _Pragma("unroll") \
    for (int d = 0; d < 4; ++d) { \
      const uint_t pk = s_pk[bb][m * N_NBRS + (gi) * 4 + d]; \
      tw##BK[d] = *(const uint4*)(wb + ((pk & 0xFFu) << 8)); \
      yt##BK[d] = *(const uint4*)(yb + ((pk >> 8) << 8)); \
    } }

#define CG(BK) { \
    _Pragma("unroll") \
    for (int d = 0; d < 4; ++d) { \
      acc[0] += bch(tw##BK[d].x) * bch(yt##BK[d].x); \
      acc[1] += bch(tw##BK[d].y) * bch(yt##BK[d].y); \
      acc[2] += bch(tw##BK[d].z) * bch(yt##BK[d].z); \
      acc[3] += bch(tw##BK[d].w) * bch(yt##BK[d].w); \
    } }

#define AGGW(bb) { \
    uint4 o; \
    o.x = hcb(acc[0]); o.y = hcb(acc[1]); o.z = hcb(acc[2]); o.w = hcb(acc[3]); \
    const int mm = m & 15; \
    *(uint4*)&aggB[bb][(m >> 4) * 2048 + mm * 128 + (((cq ^ mm) & 15) << 3)] = o; }

#define AFRAGP(P, k0) (*(const f16x8*)&(P)[rc * 128 + (((((k0) >> 3) + qk) ^ rc) & 15) * 8])

  // ---- prologue: stage chunks 0 and 1, full cfconv for chunk 0 ----
  STAGE(0, bid)
  if (1 < myChunks) STAGE(1, bid + PBLOCKS)
  __syncthreads();     // table + pk[0]/pk[1] visible
  #pragma unroll
  for (int c = 0; c < 4; ++c) acc[c] = (f16x2)0;
  IG(A, 0, 0) IG(B, 0, 1)
  CG(A) IG(A, 0, 2)
  CG(B) IG(B, 0, 3)
  CG(A) IG(A, 0, 4)
  CG(B) IG(B, 0, 5)
  CG(A) IG(A, 0, 6)
  CG(B) IG(B, 0, 7)
  CG(A)
  CG(B)
  AGGW(0)
  __syncthreads();     // aggB[0] ready

  // ---- main loop: 3 barriers per chunk ----
  for (int s = 0; s < myChunks; ++s) {
    const int b  = s & 1;
    const int cc = bid + s * PBLOCKS;
    const bool hn = (s + 1 < myChunks);
    const int nb_ = b ^ 1;

    if (hn) {
      #pragma unroll
      for (int c = 0; c < 4; ++c) acc[c] = (f16x2)0;
    }

    // Phase 1: dense L1 on aggB[b] || cfconv groups 0-2 of next chunk
    if (hn) { IG(A, nb_, 0) IG(B, nb_, 1) }
    {
      const f16* aggp = &aggB[b][g * 2048];
      f32x4 dacc[2];
      #pragma unroll
      for (int t = 0; t < 2; ++t) dacc[t] = (f32x4){bb1[t], bb1[t], bb1[t], bb1[t]};
      #pragma unroll
      for (int k0i = 0; k0i < 4; ++k0i) {
        const f16x8 af = AFRAGP(aggp, k0i * 32);
        #pragma unroll
        for (int t = 0; t < 2; ++t)
          dacc[t] = __builtin_amdgcn_mfma_f32_16x16x32_f16(af, bw1[t][k0i], dacc[t], 0, 0, 0);
      }
      f16* hB = &sB[g * 2048];
      #pragma unroll
      for (int t = 0; t < 2; ++t) {
        const int c = wvg * 32 + t * 16 + rc;
        #pragma unroll
        for (int r = 0; r < 4; ++r) hB[swz(qk * 4 + r, c)] = (f16)ssp(dacc[t][r]);
      }
    }
    if (hn) { CG(A) IG(A, nb_, 2) CG(B) CG(A) }
    __syncthreads();   // B1: sB ready

    // Phase 2: dense L2 + residual || cfconv groups 3-5
    if (hn) { IG(A, nb_, 3) IG(B, nb_, 4) }
    {
      const f16* hB = &sB[g * 2048];
      f16* hX = &sX[g * 2048];
      f32x4 dacc[2];
      #pragma unroll
      for (int t = 0; t < 2; ++t) dacc[t] = (f32x4){bb2[t], bb2[t], bb2[t], bb2[t]};
      #pragma unroll
      for (int k0i = 0; k0i < 4; ++k0i) {
        const f16x8 af = AFRAGP(hB, k0i * 32);
        #pragma unroll
        for (int t = 0; t < 2; ++t)
          dacc[t] = __builtin_amdgcn_mfma_f32_16x16x32_f16(af, bw2[t][k0i], dacc[t], 0, 0, 0);
      }
      #pragma unroll
      for (int t = 0; t < 2; ++t) {
        const int c = wvg * 32 + t * 16 + rc;
        #pragma unroll
        for (int r = 0; r < 4; ++r) {
          const int mm = qk * 4 + r;
          const float x = embed[(size_t)sZb[b][g * 16 + mm] * 128 + c] + dacc[t][r];
          hX[swz(mm, c)] = (f16)x;
        }
      }
    }
    if (hn) { CG(A) IG(A, nb_, 5) CG(B) CG(A) }
    __syncthreads();   // B2: sX ready

    // Phase 3: MLP || cfconv groups 6-7 + agg write || stage chunk s+2
    if (hn) { IG(A, nb_, 6) IG(B, nb_, 7) }
    if (s + 2 < myChunks) STAGE(b, bid + (s + 2) * PBLOCKS)  // buffer b free since B3 of s-1
    {
      const f16* hX = &sX[g * 2048];
      f32x4 a2 = (f32x4){bm, bm, bm, bm};
      #pragma unroll
      for (int k0i = 0; k0i < 4; ++k0i)
        a2 = __builtin_amdgcn_mfma_f32_16x16x32_f16(AFRAGP(hX, k0i * 32), bwm[k0i], a2, 0, 0, 0);
      #pragma unroll
      for (int r = 0; r < 4; ++r) {
        const int atom = cc * 32 + g * 16 + qk * 4 + r;
        if (atom < N_ATOMS) vsum = fmaf(ssp(a2[r]), cm, vsum);
      }
    }
    if (hn) { CG(A) CG(B) AGGW(nb_) }
    __syncthreads();   // B3: aggB[nb_] + s_pk[b] complete; sB/sX free
  }
#undef STAGE
#undef IG
#undef CG
#undef AGGW
#undef AFRAGP

  // ---- block reduce -> one atomicAdd per block ----
  #pragma unroll
  for (int o = 1; o < 64; o <<= 1) vsum += __shfl_xor(vsum, o, 64);
  if (l == 0) sRed[w] = vsum;
  __syncthreads();
  if (tid == 0) {
    float sF = 0.0f;
    #pragma unroll
    for (int i = 0; i < 8; ++i) sF += sRed[i];
    atomicAdd(out, 20.0f * sF);
  }
}

extern "C" void kernel_launch(void* const* d_in, const int* in_sizes, int n_in,
                              void* d_out, int out_size, void* d_ws, size_t ws_size,
                              hipStream_t stream) {
  const float* dR    = (const float*)d_in[0];
  const int*   Z     = (const int*)  d_in[1];
  const int*   nbr   = (const int*)  d_in[2];
  const float* embed = (const float*)d_in[3];
  const float* fw1   = (const float*)d_in[4];
  const float* fb1   = (const float*)d_in[5];
  const float* fw2   = (const float*)d_in[6];
  const float* fb2   = (const float*)d_in[7];
  const float* in2f  = (const float*)d_in[8];
  const float* w1    = (const float*)d_in[9];
  const float* b1    = (const float*)d_in[10];
  const float* w2    = (const float*)d_in[11];
  const float* b2    = (const float*)d_in[12];
  const float* mw1   = (const float*)d_in[13];
  const float* mb1   = (const float*)d_in[14];
  const float* mw2   = (const float*)d_in[15];
  const float* mb2   = (const float*)d_in[16];
  float* out = (float*)d_out;

  char* ws = (char*)d_ws;
  f16*    tabh    = (f16*)ws;                               // 22.5 KB
  f16*    ytab    = (f16*)(ws + (size_t)64 * 1024);         // 25.6 KB
  f16*    w1ht    = (f16*)(ws + (size_t)128 * 1024);        // 32 KB
  f16*    w2ht    = (f16*)(ws + (size_t)192 * 1024);        // 32 KB
  f16*    mw1ht   = (f16*)(ws + (size_t)256 * 1024);        // 16 KB
  uint_t* pkAll   = (uint_t*)(ws + (size_t)1024 * 1024);    // 6.4 MB

  prep_all_kernel<<<NTB + 64 + PKB, 256, 0, stream>>>(fw1, fb1, fw2, fb2,
      w1, w2, mw1, embed, in2f, dR, nbr, Z, mb2,
      tabh, ytab, w1ht, w2ht, mw1ht, pkAll, out);
  fused_kernel<<<PBLOCKS, 512, 0, stream>>>(pkAll, Z, embed,
      tabh, ytab, w1ht, b1, w2ht, b2, mw1ht, mb1, mw2, out);
}

// Round 22
// 58.855 us; speedup vs baseline: 1.7738x; 1.7738x over previous
//
#include <hip/hip_runtime.h>
#include <math.h>

#define N_ATOMS  50000
#define N_NBRS   32
#define N_GAUSS  25
#define RCUT     5.0f
#define TT       88        // nearest-table nodes, spacing RCUT/87 (fits 64KB LDS)
#define TROWS    32
#define NTB      3         // ceil(88/32) table-build blocks
#define MAXZ     100
#define NT32     1563      // ceil(50000/32) 32-atom chunks
#define PBLOCKS  512       // persistent fused blocks (2 per CU)
#define NPAIR    (N_ATOMS * N_NBRS)        // 1,600,000
#define PKPAD    (NT32 * 1024)             // 1,600,512 (padded)
#define PKB      782                       // pk-precompute blocks (2048 pairs each)
#define PI_F     3.14159265358979323846f

typedef unsigned int   uint_t;
typedef unsigned short ushort_t;
typedef _Float16 f16;
typedef f16   f16x2 __attribute__((ext_vector_type(2)));
typedef f16   f16x4 __attribute__((ext_vector_type(4)));
typedef f16   f16x8 __attribute__((ext_vector_type(8)));
typedef float f32x4 __attribute__((ext_vector_type(4)));

// fast shifted softplus: max(x,0) + log(0.5 + 0.5*exp(-|x|))
__device__ __forceinline__ float ssp(float x) {
  return fmaxf(x, 0.0f) + __logf(fmaf(0.5f, __expf(-fabsf(x)), 0.5f));
}
__device__ __forceinline__ f16x2 bch(uint_t u) {
  return __builtin_bit_cast(f16x2, u);
}
__device__ __forceinline__ uint_t hcb(f16x2 v) {
  return __builtin_bit_cast(uint_t, v);
}
// swizzled element offset into a [16][128] f16 LDS tile
__device__ __forceinline__ int swz(int m, int e) {
  return m * 128 + ((((e >> 3) ^ m) & 15) << 3) + (e & 7);
}

// ---- prep: [0,NTB) table; [NTB,NTB+64) transposes+ytab; [NTB+64,...) pair codes
__global__ void __launch_bounds__(256, 2)
prep_all_kernel(const float* __restrict__ fw1,
                const float* __restrict__ fb1,
                const float* __restrict__ fw2,
                const float* __restrict__ fb2,
                const float* __restrict__ w1,
                const float* __restrict__ w2,
                const float* __restrict__ mw1,
                const float* __restrict__ embed,
                const float* __restrict__ in2f,
                const float* __restrict__ dR,
                const int* __restrict__ nbr,
                const int* __restrict__ Z,
                const float* __restrict__ mb2,
                f16* __restrict__ tabh,
                f16* __restrict__ ytab,
                f16* __restrict__ w1ht,
                f16* __restrict__ w2ht,
                f16* __restrict__ mw1ht,
                uint_t* __restrict__ pkAll,
                float* __restrict__ out) {
  const int tid = threadIdx.x;
  const int bid = blockIdx.x;
  if (bid == 0 && tid == 0) {
    out[0] = 20.0f * (float)N_ATOMS * mb2[0];   // seed with bias term; fused adds the rest
  }

  __shared__ float sW2[128 * 128];       // 64 KB
  __shared__ float sH[TROWS][128];       // 16 KB

  if (bid >= NTB + 64) {
    // ---- pair-code precompute: pk = i0 | (Z[nbr] << 8) ----
    const int base = (bid - NTB - 64) * 2048;
    #pragma unroll
    for (int t0 = 0; t0 < 8; ++t0) {
      const int idx = base + t0 * 256 + tid;
      if (idx < PKPAD) {
        uint_t pk = 0;
        if (idx < NPAIR) {
          const float r = dR[idx];
          const int  nb = nbr[idx];
          int i0 = (int)(r * (87.0f / RCUT) + 0.5f);
          i0 = min(i0, 87);
          pk = (uint_t)i0 | ((uint_t)Z[nb] << 8);
        }
        pkAll[idx] = pk;
      }
    }
    return;
  }

  if (bid < NTB) {
    const int i0 = bid * TROWS;
    #pragma unroll
    for (int t = 0; t < 16; ++t) {
      const int e = tid + t * 256;
      ((float4*)sW2)[e] = ((const float4*)fw2)[e];
    }
    {
      const int f  = tid & 127;
      const int rh = (tid >> 7) * (TROWS / 2);
      const float delta = RCUT / (float)(N_GAUSS - 1);
      const float coeff = -0.5f / (delta * delta);
      const float b1v = fb1[f];
      for (int j = 0; j < TROWS / 2; ++j) {
        const float r = (float)(i0 + rh + j) * (RCUT / 87.0f);
        float h = b1v;
        #pragma unroll
        for (int g = 0; g < N_GAUSS; ++g) {
          const float d = r - (float)g * delta;
          h = fmaf(__expf(coeff * d * d), fw1[g * 128 + f], h);
        }
        sH[rh + j][f] = ssp(h);
      }
    }
    __syncthreads();
    {
      const int c0 = (tid & 31) * 4;
      const int rg = (tid >> 5) * 4;
      f32x4 acc[4];
      const float4 bv = *(const float4*)&fb2[c0];
      #pragma unroll
      for (int j = 0; j < 4; ++j) acc[j] = (f32x4){bv.x, bv.y, bv.z, bv.w};
      for (int k = 0; k < 128; ++k) {
        const float4 wv = *(const float4*)&sW2[k * 128 + c0];
        #pragma unroll
        for (int j = 0; j < 4; ++j) {
          const float hv = sH[rg + j][k];
          acc[j][0] = fmaf(hv, wv.x, acc[j][0]);
          acc[j][1] = fmaf(hv, wv.y, acc[j][1]);
          acc[j][2] = fmaf(hv, wv.z, acc[j][2]);
          acc[j][3] = fmaf(hv, wv.w, acc[j][3]);
        }
      }
      #pragma unroll
      for (int j = 0; j < 4; ++j) {
        const int i = i0 + rg + j;
        if (i < TT) {
          const float r = (float)i * (RCUT / 87.0f);
          const float fc = (r < RCUT) ? 0.5f * (__cosf(r * PI_F / RCUT) + 1.0f) : 0.0f;
          f16x4 o;
          #pragma unroll
          for (int c = 0; c < 4; ++c) o[c] = (f16)(acc[j][c] * fc);
          *(f16x4*)&tabh[i * 128 + c0] = o;
        }
      }
    }
  } else {
    const int cc = (bid - NTB) * 2 + (tid >> 7);
    const int i  = tid & 127;
    w1ht[cc * 128 + i] = (f16)w1[i * 128 + cc];
    w2ht[cc * 128 + i] = (f16)w2[i * 128 + cc];
    if (cc < 64) mw1ht[cc * 128 + i] = (f16)mw1[i * 64 + cc];
    float* xs = &sH[0][0] + (tid >> 7) * 128;
    xs[i] = (cc < MAXZ) ? embed[cc * 128 + i] : 0.0f;
    __syncthreads();
    if (cc < MAXZ) {
      float acc = 0.0f;
      for (int j = 0; j < 128; j += 4) {
        const float4 xv = *reinterpret_cast<const float4*>(&xs[j]);
        acc = fmaf(xv.x, in2f[(j + 0) * 128 + i], acc);
        acc = fmaf(xv.y, in2f[(j + 1) * 128 + i], acc);
        acc = fmaf(xv.z, in2f[(j + 2) * 128 + i], acc);
        acc = fmaf(xv.w, in2f[(j + 3) * 128 + i], acc);
      }
      ytab[cc * 128 + i] = (f16)acc;
    }
  }
}

// ---- fused kernel: same-wave cross-chunk pipeline; LDS < 64 KB (standard mode,
//      2 blocks/CU when VGPR <= 128 — no forced cap, graceful fallback).
__global__ void __launch_bounds__(512, 2)
fused_kernel(const uint_t* __restrict__ pkAll,
             const int* __restrict__ Z,
             const float* __restrict__ embed,
             const f16* __restrict__ tabh,
             const f16* __restrict__ ytab,
             const f16* __restrict__ w1ht, const float* __restrict__ b1,
             const f16* __restrict__ w2ht, const float* __restrict__ b2,
             const f16* __restrict__ mw1ht, const float* __restrict__ mb1,
             const float* __restrict__ mw2,
             float* __restrict__ out) {
  const int tid = threadIdx.x;
  const int w   = tid >> 6;         // wave 0..7
  const int l   = tid & 63;
  const int q   = l >> 4;           // quarter
  const int cq  = l & 15;
  const int bid = blockIdx.x;

  __shared__ __align__(16) f16    sW[TT * 128];      // 22.5 KB nearest table
  __shared__ __align__(16) uint_t s_pk[2][1024];     // 8 KB pair codes (dbuf)
  __shared__ __align__(16) f16    aggB[2][32 * 128]; // 16 KB agg (dbuf)
  __shared__ __align__(16) f16    sB[32 * 128];      // 8 KB h1
  __shared__ __align__(16) f16    sX[32 * 128];      // 8 KB xnew
  __shared__ int   sZb[2][32];
  __shared__ float sRed[8];
  // total ~63.8 KB < 64 KB

  for (int e = tid; e < TT * 16; e += 512) ((uint4*)sW)[e] = ((const uint4*)tabh)[e];

  // dense role indices
  const int g   = w >> 2;           // 16-atom tile within chunk
  const int wvg = w & 3;
  const int rc  = cq;
  const int qk  = q;
  f16x8 bw1[2][4], bw2[2][4], bwm[4];
  float bb1[2], bb2[2];
  #pragma unroll
  for (int t = 0; t < 2; ++t) {
    const int c = wvg * 32 + t * 16 + rc;
    bb1[t] = b1[c];
    bb2[t] = b2[c];
    #pragma unroll
    for (int k0i = 0; k0i < 4; ++k0i) {
      bw1[t][k0i] = *(const f16x8*)&w1ht[c * 128 + k0i * 32 + qk * 8];
      bw2[t][k0i] = *(const f16x8*)&w2ht[c * 128 + k0i * 32 + qk * 8];
    }
  }
  const int c1 = wvg * 16 + rc;
  #pragma unroll
  for (int k0i = 0; k0i < 4; ++k0i)
    bwm[k0i] = *(const f16x8*)&mw1ht[c1 * 128 + k0i * 32 + qk * 8];
  const float bm = mb1[c1];
  const float cm = mw2[c1];

  // cfconv role indices
  const int m = w * 4 + q;          // atom within 32-chunk
  const char* wb = (const char*)sW   + cq * 16;   // LDS table base
  const char* yb = (const char*)ytab + cq * 16;   // GLOBAL ytab base (L1-resident)

  const int myChunks = (NT32 - 1 - bid) / PBLOCKS + 1;
  float vsum = 0.0f;

  f16x2 acc[4];
  uint4 twA[4], ytA[4], twB[4], ytB[4];

#define STAGE(bb, cc) { \
    const uint2 v = *(const uint2*)&pkAll[(cc) * 1024 + tid * 2]; \
    *(uint2*)&s_pk[bb][tid * 2] = v; \
    if (tid < 32) sZb[bb][tid] = ((cc) * 32 + tid < N_ATOMS) ? Z[(cc) * 32 + tid] : 0; }

#define IG(BK, bb, gi) { \
    _Pragma("unroll") \
    for (int d = 0; d < 4; ++d) { \
      const uint_t pk = s_pk[bb][m * N_NBRS + (gi) * 4 + d]; \
      tw##BK[d] = *(const uint4*)(wb + ((pk & 0xFFu) << 8)); \
      yt##BK[d] = *(const uint4*)(yb + ((pk >> 8) << 8)); \
    } }

#define CG(BK) { \
    _Pragma("unroll") \
    for (int d = 0; d < 4; ++d) { \
      acc[0] += bch(tw##BK[d].x) * bch(yt##BK[d].x); \
      acc[1] += bch(tw##BK[d].y) * bch(yt##BK[d].y); \
      acc[2] += bch(tw##BK[d].z) * bch(yt##BK[d].z); \
      acc[3] += bch(tw##BK[d].w) * bch(yt##BK[d].w); \
    } }

#define AGGW(bb) { \
    uint4 o; \
    o.x = hcb(acc[0]); o.y = hcb(acc[1]); o.z = hcb(acc[2]); o.w = hcb(acc[3]); \
    const int mm = m & 15; \
    *(uint4*)&aggB[bb][(m >> 4) * 2048 + mm * 128 + (((cq ^ mm) & 15) << 3)] = o; }

#define AFRAGP(P, k0) (*(const f16x8*)&(P)[rc * 128 + (((((k0) >> 3) + qk) ^ rc) & 15) * 8])

  // ---- prologue: stage chunks 0 and 1, full cfconv for chunk 0 ----
  STAGE(0, bid)
  if (1 < myChunks) STAGE(1, bid + PBLOCKS)
  __syncthreads();     // table + pk[0]/pk[1] visible
  #pragma unroll
  for (int c = 0; c < 4; ++c) acc[c] = (f16x2)0;
  IG(A, 0, 0) IG(B, 0, 1)
  CG(A) IG(A, 0, 2)
  CG(B) IG(B, 0, 3)
  CG(A) IG(A, 0, 4)
  CG(B) IG(B, 0, 5)
  CG(A) IG(A, 0, 6)
  CG(B) IG(B, 0, 7)
  CG(A)
  CG(B)
  AGGW(0)
  __syncthreads();     // aggB[0] ready

  // ---- main loop: 3 barriers per chunk ----
  for (int s = 0; s < myChunks; ++s) {
    const int b  = s & 1;
    const int cc = bid + s * PBLOCKS;
    const bool hn = (s + 1 < myChunks);
    const int nb_ = b ^ 1;

    if (hn) {
      #pragma unroll
      for (int c = 0; c < 4; ++c) acc[c] = (f16x2)0;
    }

    // Phase 1: dense L1 on aggB[b] || cfconv groups 0-2 of next chunk
    if (hn) { IG(A, nb_, 0) IG(B, nb_, 1) }
    {
      const f16* aggp = &aggB[b][g * 2048];
      f32x4 dacc[2];
      #pragma unroll
      for (int t = 0; t < 2; ++t) dacc[t] = (f32x4){bb1[t], bb1[t], bb1[t], bb1[t]};
      #pragma unroll
      for (int k0i = 0; k0i < 4; ++k0i) {
        const f16x8 af = AFRAGP(aggp, k0i * 32);
        #pragma unroll
        for (int t = 0; t < 2; ++t)
          dacc[t] = __builtin_amdgcn_mfma_f32_16x16x32_f16(af, bw1[t][k0i], dacc[t], 0, 0, 0);
      }
      f16* hB = &sB[g * 2048];
      #pragma unroll
      for (int t = 0; t < 2; ++t) {
        const int c = wvg * 32 + t * 16 + rc;
        #pragma unroll
        for (int r = 0; r < 4; ++r) hB[swz(qk * 4 + r, c)] = (f16)ssp(dacc[t][r]);
      }
    }
    if (hn) { CG(A) IG(A, nb_, 2) CG(B) CG(A) }
    __syncthreads();   // B1: sB ready

    // Phase 2: dense L2 + residual || cfconv groups 3-5
    if (hn) { IG(A, nb_, 3) IG(B, nb_, 4) }
    {
      const f16* hB = &sB[g * 2048];
      f16* hX = &sX[g * 2048];
      f32x4 dacc[2];
      #pragma unroll
      for (int t = 0; t < 2; ++t) dacc[t] = (f32x4){bb2[t], bb2[t], bb2[t], bb2[t]};
      #pragma unroll
      for (int k0i = 0; k0i < 4; ++k0i) {
        const f16x8 af = AFRAGP(hB, k0i * 32);
        #pragma unroll
        for (int t = 0; t < 2; ++t)
          dacc[t] = __builtin_amdgcn_mfma_f32_16x16x32_f16(af, bw2[t][k0i], dacc[t], 0, 0, 0);
      }
      #pragma unroll
      for (int t = 0; t < 2; ++t) {
        const int c = wvg * 32 + t * 16 + rc;
        #pragma unroll
        for (int r = 0; r < 4; ++r) {
          const int mm = qk * 4 + r;
          const float x = embed[(size_t)sZb[b][g * 16 + mm] * 128 + c] + dacc[t][r];
          hX[swz(mm, c)] = (f16)x;
        }
      }
    }
    if (hn) { CG(A) IG(A, nb_, 5) CG(B) CG(A) }
    __syncthreads();   // B2: sX ready

    // Phase 3: MLP || cfconv groups 6-7 + agg write || stage chunk s+2
    if (hn) { IG(A, nb_, 6) IG(B, nb_, 7) }
    if (s + 2 < myChunks) STAGE(b, bid + (s + 2) * PBLOCKS)  // buffer b free since B3 of s-1
    {
      const f16* hX = &sX[g * 2048];
      f32x4 a2 = (f32x4){bm, bm, bm, bm};
      #pragma unroll
      for (int k0i = 0; k0i < 4; ++k0i)
        a2 = __builtin_amdgcn_mfma_f32_16x16x32_f16(AFRAGP(hX, k0i * 32), bwm[k0i], a2, 0, 0, 0);
      #pragma unroll
      for (int r = 0; r < 4; ++r) {
        const int atom = cc * 32 + g * 16 + qk * 4 + r;
        if (atom < N_ATOMS) vsum = fmaf(ssp(a2[r]), cm, vsum);
      }
    }
    if (hn) { CG(A) CG(B) AGGW(nb_) }
    __syncthreads();   // B3: aggB[nb_] + s_pk[b] complete; sB/sX free
  }
#undef STAGE
#undef IG
#undef CG
#undef AGGW
#undef AFRAGP

  // ---- block reduce -> one atomicAdd per block ----
  #pragma unroll
  for (int o = 1; o < 64; o <<= 1) vsum += __shfl_xor(vsum, o, 64);
  if (l == 0) sRed[w] = vsum;
  __syncthreads();
  if (tid == 0) {
    float sF = 0.0f;
    #pragma unroll
    for (int i = 0; i < 8; ++i) sF += sRed[i];
    atomicAdd(out, 20.0f * sF);
  }
}

extern "C" void kernel_launch(void* const* d_in, const int* in_sizes, int n_in,
                              void* d_out, int out_size, void* d_ws, size_t ws_size,
                              hipStream_t stream) {
  const float* dR    = (const float*)d_in[0];
  const int*   Z     = (const int*)  d_in[1];
  const int*   nbr   = (const int*)  d_in[2];
  const float* embed = (const float*)d_in[3];
  const float* fw1   = (const float*)d_in[4];
  const float* fb1   = (const float*)d_in[5];
  const float* fw2   = (const float*)d_in[6];
  const float* fb2   = (const float*)d_in[7];
  const float* in2f  = (const float*)d_in[8];
  const float* w1    = (const float*)d_in[9];
  const float* b1    = (const float*)d_in[10];
  const float* w2    = (const float*)d_in[11];
  const float* b2    = (const float*)d_in[12];
  const float* mw1   = (const float*)d_in[13];
  const float* mb1   = (const float*)d_in[14];
  const float* mw2   = (const float*)d_in[15];
  const float* mb2   = (const float*)d_in[16];
  float* out = (float*)d_out;

  char* ws = (char*)d_ws;
  f16*    tabh    = (f16*)ws;                               // 22.5 KB
  f16*    ytab    = (f16*)(ws + (size_t)64 * 1024);         // 25.6 KB
  f16*    w1ht    = (f16*)(ws + (size_t)128 * 1024);        // 32 KB
  f16*    w2ht    = (f16*)(ws + (size_t)192 * 1024);        // 32 KB
  f16*    mw1ht   = (f16*)(ws + (size_t)256 * 1024);        // 16 KB
  uint_t* pkAll   = (uint_t*)(ws + (size_t)1024 * 1024);    // 6.4 MB

  prep_all_kernel<<<NTB + 64 + PKB, 256, 0, stream>>>(fw1, fb1, fw2, fb2,
      w1, w2, mw1, embed, in2f, dR, nbr, Z, mb2,
      tabh, ytab, w1ht, w2ht, mw1ht, pkAll, out);
  fused_kernel<<<PBLOCKS, 512, 0, stream>>>(pkAll, Z, embed,
      tabh, ytab, w1ht, b1, w2ht, b2, mw1ht, mb1, mw2, out);
}

// Round 23
// 57.021 us; speedup vs baseline: 1.8309x; 1.0322x over previous
//
#include <hip/hip_runtime.h>
#include <math.h>

#define N_ATOMS  50000
#define N_NBRS   32
#define N_GAUSS  25
#define RCUT     5.0f
#define TT       88        // nearest-table nodes, spacing RCUT/87
#define TROWS    32
#define NTB      3         // ceil(88/32) table-build blocks
#define MAXZ     100
#define NCH      3125      // 50000/16 16-atom chunks (exact)
#define PBLOCKS  1024      // persistent fused blocks (target 3-4 per CU)
#define NPAIR    (N_ATOMS * N_NBRS)        // 1,600,000
#define PKB      782                       // pk-precompute blocks (2048 pairs each)
#define PI_F     3.14159265358979323846f

typedef unsigned int   uint_t;
typedef unsigned short ushort_t;
typedef _Float16 f16;
typedef f16   f16x2 __attribute__((ext_vector_type(2)));
typedef f16   f16x4 __attribute__((ext_vector_type(4)));
typedef f16   f16x8 __attribute__((ext_vector_type(8)));
typedef float f32x4 __attribute__((ext_vector_type(4)));

// fast shifted softplus: max(x,0) + log(0.5 + 0.5*exp(-|x|))
__device__ __forceinline__ float ssp(float x) {
  return fmaxf(x, 0.0f) + __logf(fmaf(0.5f, __expf(-fabsf(x)), 0.5f));
}
__device__ __forceinline__ f16x2 bch(uint_t u) {
  return __builtin_bit_cast(f16x2, u);
}
__device__ __forceinline__ uint_t hcb(f16x2 v) {
  return __builtin_bit_cast(uint_t, v);
}
// swizzled element offset into a [16][128] f16 LDS tile
__device__ __forceinline__ int swz(int m, int e) {
  return m * 128 + ((((e >> 3) ^ m) & 15) << 3) + (e & 7);
}

// ---- prep: [0,NTB) table; [NTB,NTB+64) transposes+ytab; [NTB+64,...) pair codes
__global__ void __launch_bounds__(256, 2)
prep_all_kernel(const float* __restrict__ fw1,
                const float* __restrict__ fb1,
                const float* __restrict__ fw2,
                const float* __restrict__ fb2,
                const float* __restrict__ w1,
                const float* __restrict__ w2,
                const float* __restrict__ mw1,
                const float* __restrict__ embed,
                const float* __restrict__ in2f,
                const float* __restrict__ dR,
                const int* __restrict__ nbr,
                const int* __restrict__ Z,
                const float* __restrict__ mb2,
                f16* __restrict__ tabh,
                f16* __restrict__ ytab,
                f16* __restrict__ w1ht,
                f16* __restrict__ w2ht,
                f16* __restrict__ mw1ht,
                uint_t* __restrict__ pkAll,
                float* __restrict__ out) {
  const int tid = threadIdx.x;
  const int bid = blockIdx.x;
  if (bid == 0 && tid == 0) {
    out[0] = 20.0f * (float)N_ATOMS * mb2[0];   // seed with bias term; fused adds the rest
  }

  __shared__ float sW2[128 * 128];       // 64 KB
  __shared__ float sH[TROWS][128];       // 16 KB

  if (bid >= NTB + 64) {
    // ---- pair-code precompute: pk = i0 | (Z[nbr] << 8) ----
    const int base = (bid - NTB - 64) * 2048;
    #pragma unroll
    for (int t0 = 0; t0 < 8; ++t0) {
      const int idx = base + t0 * 256 + tid;
      if (idx < NPAIR) {
        const float r = dR[idx];
        const int  nb = nbr[idx];
        int i0 = (int)(r * (87.0f / RCUT) + 0.5f);
        i0 = min(i0, 87);
        pkAll[idx] = (uint_t)i0 | ((uint_t)Z[nb] << 8);
      }
    }
    return;
  }

  if (bid < NTB) {
    const int i0 = bid * TROWS;
    #pragma unroll
    for (int t = 0; t < 16; ++t) {
      const int e = tid + t * 256;
      ((float4*)sW2)[e] = ((const float4*)fw2)[e];
    }
    {
      const int f  = tid & 127;
      const int rh = (tid >> 7) * (TROWS / 2);
      const float delta = RCUT / (float)(N_GAUSS - 1);
      const float coeff = -0.5f / (delta * delta);
      const float b1v = fb1[f];
      for (int j = 0; j < TROWS / 2; ++j) {
        const float r = (float)(i0 + rh + j) * (RCUT / 87.0f);
        float h = b1v;
        #pragma unroll
        for (int g = 0; g < N_GAUSS; ++g) {
          const float d = r - (float)g * delta;
          h = fmaf(__expf(coeff * d * d), fw1[g * 128 + f], h);
        }
        sH[rh + j][f] = ssp(h);
      }
    }
    __syncthreads();
    {
      const int c0 = (tid & 31) * 4;
      const int rg = (tid >> 5) * 4;
      f32x4 acc[4];
      const float4 bv = *(const float4*)&fb2[c0];
      #pragma unroll
      for (int j = 0; j < 4; ++j) acc[j] = (f32x4){bv.x, bv.y, bv.z, bv.w};
      for (int k = 0; k < 128; ++k) {
        const float4 wv = *(const float4*)&sW2[k * 128 + c0];
        #pragma unroll
        for (int j = 0; j < 4; ++j) {
          const float hv = sH[rg + j][k];
          acc[j][0] = fmaf(hv, wv.x, acc[j][0]);
          acc[j][1] = fmaf(hv, wv.y, acc[j][1]);
          acc[j][2] = fmaf(hv, wv.z, acc[j][2]);
          acc[j][3] = fmaf(hv, wv.w, acc[j][3]);
        }
      }
      #pragma unroll
      for (int j = 0; j < 4; ++j) {
        const int i = i0 + rg + j;
        if (i < TT) {
          const float r = (float)i * (RCUT / 87.0f);
          const float fc = (r < RCUT) ? 0.5f * (__cosf(r * PI_F / RCUT) + 1.0f) : 0.0f;
          f16x4 o;
          #pragma unroll
          for (int c = 0; c < 4; ++c) o[c] = (f16)(acc[j][c] * fc);
          *(f16x4*)&tabh[i * 128 + c0] = o;
        }
      }
    }
  } else {
    const int cc = (bid - NTB) * 2 + (tid >> 7);
    const int i  = tid & 127;
    w1ht[cc * 128 + i] = (f16)w1[i * 128 + cc];
    w2ht[cc * 128 + i] = (f16)w2[i * 128 + cc];
    if (cc < 64) mw1ht[cc * 128 + i] = (f16)mw1[i * 64 + cc];
    float* xs = &sH[0][0] + (tid >> 7) * 128;
    xs[i] = (cc < MAXZ) ? embed[cc * 128 + i] : 0.0f;
    __syncthreads();
    if (cc < MAXZ) {
      float acc = 0.0f;
      for (int j = 0; j < 128; j += 4) {
        const float4 xv = *reinterpret_cast<const float4*>(&xs[j]);
        acc = fmaf(xv.x, in2f[(j + 0) * 128 + i], acc);
        acc = fmaf(xv.y, in2f[(j + 1) * 128 + i], acc);
        acc = fmaf(xv.z, in2f[(j + 2) * 128 + i], acc);
        acc = fmaf(xv.w, in2f[(j + 3) * 128 + i], acc);
      }
      ytab[cc * 128 + i] = (f16)acc;
    }
  }
}

// ---- fused kernel: 256-thread (4-wave) persistent blocks, 16-atom chunks,
//      same-wave cross-chunk pipeline, 3 barriers/chunk; LDS ~42 KB so the
//      CU can co-schedule 2-3 blocks (cross-block TLP fills barrier stalls).
__global__ void __launch_bounds__(256, 2)
fused_kernel(const uint_t* __restrict__ pkAll,
             const int* __restrict__ Z,
             const float* __restrict__ embed,
             const f16* __restrict__ tabh,
             const f16* __restrict__ ytab,
             const f16* __restrict__ w1ht, const float* __restrict__ b1,
             const f16* __restrict__ w2ht, const float* __restrict__ b2,
             const f16* __restrict__ mw1ht, const float* __restrict__ mb1,
             const float* __restrict__ mw2,
             float* __restrict__ out) {
  const int tid = threadIdx.x;
  const int w   = tid >> 6;         // wave 0..3
  const int l   = tid & 63;
  const int q   = l >> 4;           // quarter
  const int cq  = l & 15;
  const int bid = blockIdx.x;

  __shared__ __align__(16) f16    sW[TT * 128];      // 22.5 KB nearest table
  __shared__ __align__(16) uint_t s_pk[2][512];      // 4 KB pair codes (dbuf)
  __shared__ __align__(16) f16    aggB[2][16 * 128]; // 8 KB agg (dbuf)
  __shared__ __align__(16) f16    sB[16 * 128];      // 4 KB h1
  __shared__ __align__(16) f16    sX[16 * 128];      // 4 KB xnew
  __shared__ int   sZb[2][16];
  __shared__ float sRed[4];
  // total ~42.2 KB

  for (int e = tid; e < TT * 16; e += 256) ((uint4*)sW)[e] = ((const uint4*)tabh)[e];

  // dense role indices (4 waves cover the 16-atom tile)
  const int rc  = cq;
  const int qk  = q;
  f16x8 bw1[2][4], bw2[2][4], bwm[4];
  float bb1[2], bb2[2];
  #pragma unroll
  for (int t = 0; t < 2; ++t) {
    const int c = w * 32 + t * 16 + rc;
    bb1[t] = b1[c];
    bb2[t] = b2[c];
    #pragma unroll
    for (int k0i = 0; k0i < 4; ++k0i) {
      bw1[t][k0i] = *(const f16x8*)&w1ht[c * 128 + k0i * 32 + qk * 8];
      bw2[t][k0i] = *(const f16x8*)&w2ht[c * 128 + k0i * 32 + qk * 8];
    }
  }
  const int c1 = w * 16 + rc;
  #pragma unroll
  for (int k0i = 0; k0i < 4; ++k0i)
    bwm[k0i] = *(const f16x8*)&mw1ht[c1 * 128 + k0i * 32 + qk * 8];
  const float bm = mb1[c1];
  const float cm = mw2[c1];

  // cfconv role indices
  const int m = w * 4 + q;          // atom within 16-chunk
  const char* wb = (const char*)sW   + cq * 16;   // LDS table base
  const char* yb = (const char*)ytab + cq * 16;   // GLOBAL ytab base (L1-resident)

  const int myChunks = (NCH - 1 - bid) / PBLOCKS + 1;
  float vsum = 0.0f;

  f16x2 acc[4];
  uint4 twA[4], ytA[4], twB[4], ytB[4];

#define STAGE(bb, cc) { \
    const uint2 v = *(const uint2*)&pkAll[(cc) * 512 + tid * 2]; \
    *(uint2*)&s_pk[bb][tid * 2] = v; \
    if (tid < 16) sZb[bb][tid] = Z[(cc) * 16 + tid]; }

#define IG(BK, bb, gi) { \
    _Pragma("unroll") \
    for (int d = 0; d < 4; ++d) { \
      const uint_t pk = s_pk[bb][m * N_NBRS + (gi) * 4 + d]; \
      tw##BK[d] = *(const uint4*)(wb + ((pk & 0xFFu) << 8)); \
      yt##BK[d] = *(const uint4*)(yb + ((pk >> 8) << 8)); \
    } }

#define CG(BK) { \
    _Pragma("unroll") \
    for (int d = 0; d < 4; ++d) { \
      acc[0] += bch(tw##BK[d].x) * bch(yt##BK[d].x); \
      acc[1] += bch(tw##BK[d].y) * bch(yt##BK[d].y); \
      acc[2] += bch(tw##BK[d].z) * bch(yt##BK[d].z); \
      acc[3] += bch(tw##BK[d].w) * bch(yt##BK[d].w); \
    } }

#define AGGW(bb) { \
    uint4 o; \
    o.x = hcb(acc[0]); o.y = hcb(acc[1]); o.z = hcb(acc[2]); o.w = hcb(acc[3]); \
    *(uint4*)&aggB[bb][m * 128 + (((cq ^ m) & 15) << 3)] = o; }

#define AFRAGP(P, k0) (*(const f16x8*)&(P)[rc * 128 + (((((k0) >> 3) + qk) ^ rc) & 15) * 8])

  // ---- prologue: stage chunks 0 and 1, full cfconv for chunk 0 ----
  STAGE(0, bid)
  if (1 < myChunks) STAGE(1, bid + PBLOCKS)
  __syncthreads();     // table + pk[0]/pk[1] visible
  #pragma unroll
  for (int c = 0; c < 4; ++c) acc[c] = (f16x2)0;
  IG(A, 0, 0) IG(B, 0, 1)
  CG(A) IG(A, 0, 2)
  CG(B) IG(B, 0, 3)
  CG(A) IG(A, 0, 4)
  CG(B) IG(B, 0, 5)
  CG(A) IG(A, 0, 6)
  CG(B) IG(B, 0, 7)
  CG(A)
  CG(B)
  AGGW(0)
  __syncthreads();     // aggB[0] ready

  // ---- main loop: 3 barriers per chunk ----
  for (int s = 0; s < myChunks; ++s) {
    const int b  = s & 1;
    const int cc = bid + s * PBLOCKS;
    const bool hn = (s + 1 < myChunks);
    const int nb_ = b ^ 1;

    if (hn) {
      #pragma unroll
      for (int c = 0; c < 4; ++c) acc[c] = (f16x2)0;
    }

    // Phase 1: dense L1 on aggB[b] || cfconv groups 0-2 of next chunk
    if (hn) { IG(A, nb_, 0) IG(B, nb_, 1) }
    {
      const f16* aggp = &aggB[b][0];
      f32x4 dacc[2];
      #pragma unroll
      for (int t = 0; t < 2; ++t) dacc[t] = (f32x4){bb1[t], bb1[t], bb1[t], bb1[t]};
      #pragma unroll
      for (int k0i = 0; k0i < 4; ++k0i) {
        const f16x8 af = AFRAGP(aggp, k0i * 32);
        #pragma unroll
        for (int t = 0; t < 2; ++t)
          dacc[t] = __builtin_amdgcn_mfma_f32_16x16x32_f16(af, bw1[t][k0i], dacc[t], 0, 0, 0);
      }
      #pragma unroll
      for (int t = 0; t < 2; ++t) {
        const int c = w * 32 + t * 16 + rc;
        #pragma unroll
        for (int r = 0; r < 4; ++r) sB[swz(qk * 4 + r, c)] = (f16)ssp(dacc[t][r]);
      }
    }
    if (hn) { CG(A) IG(A, nb_, 2) CG(B) CG(A) }
    __syncthreads();   // B1: sB ready

    // Phase 2: dense L2 + residual || cfconv groups 3-5
    if (hn) { IG(A, nb_, 3) IG(B, nb_, 4) }
    {
      f32x4 dacc[2];
      #pragma unroll
      for (int t = 0; t < 2; ++t) dacc[t] = (f32x4){bb2[t], bb2[t], bb2[t], bb2[t]};
      #pragma unroll
      for (int k0i = 0; k0i < 4; ++k0i) {
        const f16x8 af = AFRAGP(sB, k0i * 32);
        #pragma unroll
        for (int t = 0; t < 2; ++t)
          dacc[t] = __builtin_amdgcn_mfma_f32_16x16x32_f16(af, bw2[t][k0i], dacc[t], 0, 0, 0);
      }
      #pragma unroll
      for (int t = 0; t < 2; ++t) {
        const int c = w * 32 + t * 16 + rc;
        #pragma unroll
        for (int r = 0; r < 4; ++r) {
          const int mm = qk * 4 + r;
          const float x = embed[(size_t)sZb[b][mm] * 128 + c] + dacc[t][r];
          sX[swz(mm, c)] = (f16)x;
        }
      }
    }
    if (hn) { CG(A) IG(A, nb_, 5) CG(B) CG(A) }
    __syncthreads();   // B2: sX ready

    // Phase 3: MLP || cfconv groups 6-7 + agg write || stage chunk s+2
    if (hn) { IG(A, nb_, 6) IG(B, nb_, 7) }
    if (s + 2 < myChunks) STAGE(b, bid + (s + 2) * PBLOCKS)  // buffer b free since B3 of s-1
    {
      f32x4 a2 = (f32x4){bm, bm, bm, bm};
      #pragma unroll
      for (int k0i = 0; k0i < 4; ++k0i)
        a2 = __builtin_amdgcn_mfma_f32_16x16x32_f16(AFRAGP(sX, k0i * 32), bwm[k0i], a2, 0, 0, 0);
      #pragma unroll
      for (int r = 0; r < 4; ++r) vsum = fmaf(ssp(a2[r]), cm, vsum);
    }
    if (hn) { CG(A) CG(B) AGGW(nb_) }
    __syncthreads();   // B3: aggB[nb_] + s_pk[b] complete; sB/sX free
  }
#undef STAGE
#undef IG
#undef CG
#undef AGGW
#undef AFRAGP

  // ---- block reduce -> one atomicAdd per block ----
  #pragma unroll
  for (int o = 1; o < 64; o <<= 1) vsum += __shfl_xor(vsum, o, 64);
  if (l == 0) sRed[w] = vsum;
  __syncthreads();
  if (tid == 0) {
    atomicAdd(out, 20.0f * (sRed[0] + sRed[1] + sRed[2] + sRed[3]));
  }
}

extern "C" void kernel_launch(void* const* d_in, const int* in_sizes, int n_in,
                              void* d_out, int out_size, void* d_ws, size_t ws_size,
                              hipStream_t stream) {
  const float* dR    = (const float*)d_in[0];
  const int*   Z     = (const int*)  d_in[1];
  const int*   nbr   = (const int*)  d_in[2];
  const float* embed = (const float*)d_in[3];
  const float* fw1   = (const float*)d_in[4];
  const float* fb1   = (const float*)d_in[5];
  const float* fw2   = (const float*)d_in[6];
  const float* fb2   = (const float*)d_in[7];
  const float* in2f  = (const float*)d_in[8];
  const float* w1    = (const float*)d_in[9];
  const float* b1    = (const float*)d_in[10];
  const float* w2    = (const float*)d_in[11];
  const float* b2    = (const float*)d_in[12];
  const float* mw1   = (const float*)d_in[13];
  const float* mb1   = (const float*)d_in[14];
  const float* mw2   = (const float*)d_in[15];
  const float* mb2   = (const float*)d_in[16];
  float* out = (float*)d_out;

  char* ws = (char*)d_ws;
  f16*    tabh    = (f16*)ws;                               // 22.5 KB
  f16*    ytab    = (f16*)(ws + (size_t)64 * 1024);         // 25.6 KB
  f16*    w1ht    = (f16*)(ws + (size_t)128 * 1024);        // 32 KB
  f16*    w2ht    = (f16*)(ws + (size_t)192 * 1024);        // 32 KB
  f16*    mw1ht   = (f16*)(ws + (size_t)256 * 1024);        // 16 KB
  uint_t* pkAll   = (uint_t*)(ws + (size_t)1024 * 1024);    // 6.4 MB

  prep_all_kernel<<<NTB + 64 + PKB, 256, 0, stream>>>(fw1, fb1, fw2, fb2,
      w1, w2, mw1, embed, in2f, dR, nbr, Z, mb2,
      tabh, ytab, w1ht, w2ht, mw1ht, pkAll, out);
  fused_kernel<<<PBLOCKS, 256, 0, stream>>>(pkAll, Z, embed,
      tabh, ytab, w1ht, b1, w2ht, b2, mw1ht, mb1, mw2, out);
}

// Round 24
// 54.950 us; speedup vs baseline: 1.8999x; 1.0377x over previous
//
#include <hip/hip_runtime.h>
#include <math.h>

#define N_ATOMS  50000
#define N_NBRS   32
#define N_GAUSS  25
#define RCUT     5.0f
#define TT       64        // nearest-table nodes, spacing RCUT/63 (all-LDS <64KB)
#define TROWS    32
#define NTB      2         // 64/32 table-build blocks
#define MAXZ     100
#define NCH      3125      // 50000/16 16-atom chunks (exact)
#define PBLOCKS  1024      // persistent fused blocks
#define NPAIR    (N_ATOMS * N_NBRS)        // 1,600,000
#define PKB      782                       // pk-precompute blocks (2048 pairs each)
#define PI_F     3.14159265358979323846f

typedef unsigned int   uint_t;
typedef unsigned short ushort_t;
typedef _Float16 f16;
typedef f16   f16x2 __attribute__((ext_vector_type(2)));
typedef f16   f16x4 __attribute__((ext_vector_type(4)));
typedef f16   f16x8 __attribute__((ext_vector_type(8)));
typedef float f32x4 __attribute__((ext_vector_type(4)));

// fast shifted softplus: max(x,0) + log(0.5 + 0.5*exp(-|x|))
__device__ __forceinline__ float ssp(float x) {
  return fmaxf(x, 0.0f) + __logf(fmaf(0.5f, __expf(-fabsf(x)), 0.5f));
}
__device__ __forceinline__ f16x2 bch(uint_t u) {
  return __builtin_bit_cast(f16x2, u);
}
__device__ __forceinline__ uint_t hcb(f16x2 v) {
  return __builtin_bit_cast(uint_t, v);
}
// swizzled element offset into a [16][128] f16 LDS tile
__device__ __forceinline__ int swz(int m, int e) {
  return m * 128 + ((((e >> 3) ^ m) & 15) << 3) + (e & 7);
}

// ---- prep: [0,NTB) table; [NTB,NTB+64) transposes+ytab; [NTB+64,...) pair codes
__global__ void __launch_bounds__(256, 2)
prep_all_kernel(const float* __restrict__ fw1,
                const float* __restrict__ fb1,
                const float* __restrict__ fw2,
                const float* __restrict__ fb2,
                const float* __restrict__ w1,
                const float* __restrict__ w2,
                const float* __restrict__ mw1,
                const float* __restrict__ embed,
                const float* __restrict__ in2f,
                const float* __restrict__ dR,
                const int* __restrict__ nbr,
                const int* __restrict__ Z,
                const float* __restrict__ mb2,
                f16* __restrict__ tabh,
                f16* __restrict__ ytab,
                f16* __restrict__ w1ht,
                f16* __restrict__ w2ht,
                f16* __restrict__ mw1ht,
                uint_t* __restrict__ pkAll,
                float* __restrict__ out) {
  const int tid = threadIdx.x;
  const int bid = blockIdx.x;
  if (bid == 0 && tid == 0) {
    out[0] = 20.0f * (float)N_ATOMS * mb2[0];   // seed with bias term; fused adds the rest
  }

  __shared__ float sW2[128 * 128];       // 64 KB
  __shared__ float sH[TROWS][128];       // 16 KB

  if (bid >= NTB + 64) {
    // ---- pair-code precompute: pk = i0 | (Z[nbr] << 8) ----
    const int base = (bid - NTB - 64) * 2048;
    #pragma unroll
    for (int t0 = 0; t0 < 8; ++t0) {
      const int idx = base + t0 * 256 + tid;
      if (idx < NPAIR) {
        const float r = dR[idx];
        const int  nb = nbr[idx];
        int i0 = (int)(r * (63.0f / RCUT) + 0.5f);
        i0 = min(i0, 63);
        pkAll[idx] = (uint_t)i0 | ((uint_t)Z[nb] << 8);
      }
    }
    return;
  }

  if (bid < NTB) {
    const int i0 = bid * TROWS;
    #pragma unroll
    for (int t = 0; t < 16; ++t) {
      const int e = tid + t * 256;
      ((float4*)sW2)[e] = ((const float4*)fw2)[e];
    }
    {
      const int f  = tid & 127;
      const int rh = (tid >> 7) * (TROWS / 2);
      const float delta = RCUT / (float)(N_GAUSS - 1);
      const float coeff = -0.5f / (delta * delta);
      const float b1v = fb1[f];
      for (int j = 0; j < TROWS / 2; ++j) {
        const float r = (float)(i0 + rh + j) * (RCUT / 63.0f);
        float h = b1v;
        #pragma unroll
        for (int g = 0; g < N_GAUSS; ++g) {
          const float d = r - (float)g * delta;
          h = fmaf(__expf(coeff * d * d), fw1[g * 128 + f], h);
        }
        sH[rh + j][f] = ssp(h);
      }
    }
    __syncthreads();
    {
      const int c0 = (tid & 31) * 4;
      const int rg = (tid >> 5) * 4;
      f32x4 acc[4];
      const float4 bv = *(const float4*)&fb2[c0];
      #pragma unroll
      for (int j = 0; j < 4; ++j) acc[j] = (f32x4){bv.x, bv.y, bv.z, bv.w};
      for (int k = 0; k < 128; ++k) {
        const float4 wv = *(const float4*)&sW2[k * 128 + c0];
        #pragma unroll
        for (int j = 0; j < 4; ++j) {
          const float hv = sH[rg + j][k];
          acc[j][0] = fmaf(hv, wv.x, acc[j][0]);
          acc[j][1] = fmaf(hv, wv.y, acc[j][1]);
          acc[j][2] = fmaf(hv, wv.z, acc[j][2]);
          acc[j][3] = fmaf(hv, wv.w, acc[j][3]);
        }
      }
      #pragma unroll
      for (int j = 0; j < 4; ++j) {
        const int i = i0 + rg + j;
        const float r = (float)i * (RCUT / 63.0f);
        const float fc = (r < RCUT) ? 0.5f * (__cosf(r * PI_F / RCUT) + 1.0f) : 0.0f;
        f16x4 o;
        #pragma unroll
        for (int c = 0; c < 4; ++c) o[c] = (f16)(acc[j][c] * fc);
        *(f16x4*)&tabh[i * 128 + c0] = o;
      }
    }
  } else {
    const int cc = (bid - NTB) * 2 + (tid >> 7);
    const int i  = tid & 127;
    w1ht[cc * 128 + i] = (f16)w1[i * 128 + cc];
    w2ht[cc * 128 + i] = (f16)w2[i * 128 + cc];
    if (cc < 64) mw1ht[cc * 128 + i] = (f16)mw1[i * 64 + cc];
    float* xs = &sH[0][0] + (tid >> 7) * 128;
    xs[i] = (cc < MAXZ) ? embed[cc * 128 + i] : 0.0f;
    __syncthreads();
    if (cc < MAXZ) {
      float acc = 0.0f;
      for (int j = 0; j < 128; j += 4) {
        const float4 xv = *reinterpret_cast<const float4*>(&xs[j]);
        acc = fmaf(xv.x, in2f[(j + 0) * 128 + i], acc);
        acc = fmaf(xv.y, in2f[(j + 1) * 128 + i], acc);
        acc = fmaf(xv.z, in2f[(j + 2) * 128 + i], acc);
        acc = fmaf(xv.w, in2f[(j + 3) * 128 + i], acc);
      }
      ytab[cc * 128 + i] = (f16)acc;
    }
  }
}

// ---- fused kernel: 256-thread (4-wave) persistent blocks, 16-atom chunks,
//      BOTH gather tables LDS-resident, total LDS ~61.7 KB (<64 KB standard
//      mode -> 2 blocks/CU co-residency possible), 3 barriers/chunk.
__global__ void __launch_bounds__(256, 2)
fused_kernel(const uint_t* __restrict__ pkAll,
             const int* __restrict__ Z,
             const float* __restrict__ embed,
             const f16* __restrict__ tabh,
             const f16* __restrict__ ytab,
             const f16* __restrict__ w1ht, const float* __restrict__ b1,
             const f16* __restrict__ w2ht, const float* __restrict__ b2,
             const f16* __restrict__ mw1ht, const float* __restrict__ mb1,
             const float* __restrict__ mw2,
             float* __restrict__ out) {
  const int tid = threadIdx.x;
  const int w   = tid >> 6;         // wave 0..3
  const int l   = tid & 63;
  const int q   = l >> 4;           // quarter
  const int cq  = l & 15;
  const int bid = blockIdx.x;

  __shared__ __align__(16) f16    sW[TT * 128];      // 16 KB nearest table
  __shared__ __align__(16) f16    sYT[MAXZ * 128];   // 25.6 KB y rows
  __shared__ __align__(16) uint_t s_pk[2][512];      // 4 KB pair codes (dbuf)
  __shared__ __align__(16) f16    aggB[2][16 * 128]; // 8 KB agg (dbuf)
  __shared__ __align__(16) f16    sB[16 * 128];      // 4 KB h1
  __shared__ __align__(16) f16    sX[16 * 128];      // 4 KB xnew
  __shared__ int   sZb[2][16];
  __shared__ float sRed[4];
  // total ~61.7 KB < 64 KB

  for (int e = tid; e < TT * 16; e += 256)   ((uint4*)sW)[e]  = ((const uint4*)tabh)[e];
  for (int e = tid; e < MAXZ * 16; e += 256) ((uint4*)sYT)[e] = ((const uint4*)ytab)[e];

  // dense role indices (4 waves cover the 16-atom tile)
  const int rc  = cq;
  const int qk  = q;
  f16x8 bw1[2][4], bw2[2][4], bwm[4];
  float bb1[2], bb2[2];
  #pragma unroll
  for (int t = 0; t < 2; ++t) {
    const int c = w * 32 + t * 16 + rc;
    bb1[t] = b1[c];
    bb2[t] = b2[c];
    #pragma unroll
    for (int k0i = 0; k0i < 4; ++k0i) {
      bw1[t][k0i] = *(const f16x8*)&w1ht[c * 128 + k0i * 32 + qk * 8];
      bw2[t][k0i] = *(const f16x8*)&w2ht[c * 128 + k0i * 32 + qk * 8];
    }
  }
  const int c1 = w * 16 + rc;
  #pragma unroll
  for (int k0i = 0; k0i < 4; ++k0i)
    bwm[k0i] = *(const f16x8*)&mw1ht[c1 * 128 + k0i * 32 + qk * 8];
  const float bm = mb1[c1];
  const float cm = mw2[c1];

  // cfconv role indices
  const int m = w * 4 + q;          // atom within 16-chunk
  const char* wb = (const char*)sW  + cq * 16;
  const char* yb = (const char*)sYT + cq * 16;

  const int myChunks = (NCH - 1 - bid) / PBLOCKS + 1;
  float vsum = 0.0f;

  f16x2 acc[4];
  uint4 twA[4], ytA[4], twB[4], ytB[4];

#define STAGE(bb, cc) { \
    const uint2 v = *(const uint2*)&pkAll[(cc) * 512 + tid * 2]; \
    *(uint2*)&s_pk[bb][tid * 2] = v; \
    if (tid < 16) sZb[bb][tid] = Z[(cc) * 16 + tid]; }

#define IG(BK, bb, gi) { \
    _Pragma("unroll") \
    for (int d = 0; d < 4; ++d) { \
      const uint_t pk = s_pk[bb][m * N_NBRS + (gi) * 4 + d]; \
      tw##BK[d] = *(const uint4*)(wb + ((pk & 0xFFu) << 8)); \
      yt##BK[d] = *(const uint4*)(yb + ((pk >> 8) << 8)); \
    } }

#define CG(BK) { \
    _Pragma("unroll") \
    for (int d = 0; d < 4; ++d) { \
      acc[0] += bch(tw##BK[d].x) * bch(yt##BK[d].x); \
      acc[1] += bch(tw##BK[d].y) * bch(yt##BK[d].y); \
      acc[2] += bch(tw##BK[d].z) * bch(yt##BK[d].z); \
      acc[3] += bch(tw##BK[d].w) * bch(yt##BK[d].w); \
    } }

#define AGGW(bb) { \
    uint4 o; \
    o.x = hcb(acc[0]); o.y = hcb(acc[1]); o.z = hcb(acc[2]); o.w = hcb(acc[3]); \
    *(uint4*)&aggB[bb][m * 128 + (((cq ^ m) & 15) << 3)] = o; }

#define AFRAGP(P, k0) (*(const f16x8*)&(P)[rc * 128 + (((((k0) >> 3) + qk) ^ rc) & 15) * 8])

  // ---- prologue: stage chunks 0 and 1, full cfconv for chunk 0 ----
  STAGE(0, bid)
  if (1 < myChunks) STAGE(1, bid + PBLOCKS)
  __syncthreads();     // tables + pk[0]/pk[1] visible
  #pragma unroll
  for (int c = 0; c < 4; ++c) acc[c] = (f16x2)0;
  IG(A, 0, 0) IG(B, 0, 1)
  CG(A) IG(A, 0, 2)
  CG(B) IG(B, 0, 3)
  CG(A) IG(A, 0, 4)
  CG(B) IG(B, 0, 5)
  CG(A) IG(A, 0, 6)
  CG(B) IG(B, 0, 7)
  CG(A)
  CG(B)
  AGGW(0)
  __syncthreads();     // aggB[0] ready

  // ---- main loop: 3 barriers per chunk ----
  for (int s = 0; s < myChunks; ++s) {
    const int b  = s & 1;
    const bool hn = (s + 1 < myChunks);
    const int nb_ = b ^ 1;

    if (hn) {
      #pragma unroll
      for (int c = 0; c < 4; ++c) acc[c] = (f16x2)0;
    }

    // Phase 1: dense L1 on aggB[b] || cfconv groups 0-2 of next chunk
    if (hn) { IG(A, nb_, 0) IG(B, nb_, 1) }
    {
      const f16* aggp = &aggB[b][0];
      f32x4 dacc[2];
      #pragma unroll
      for (int t = 0; t < 2; ++t) dacc[t] = (f32x4){bb1[t], bb1[t], bb1[t], bb1[t]};
      #pragma unroll
      for (int k0i = 0; k0i < 4; ++k0i) {
        const f16x8 af = AFRAGP(aggp, k0i * 32);
        #pragma unroll
        for (int t = 0; t < 2; ++t)
          dacc[t] = __builtin_amdgcn_mfma_f32_16x16x32_f16(af, bw1[t][k0i], dacc[t], 0, 0, 0);
      }
      #pragma unroll
      for (int t = 0; t < 2; ++t) {
        const int c = w * 32 + t * 16 + rc;
        #pragma unroll
        for (int r = 0; r < 4; ++r) sB[swz(qk * 4 + r, c)] = (f16)ssp(dacc[t][r]);
      }
    }
    if (hn) { CG(A) IG(A, nb_, 2) CG(B) CG(A) }
    __syncthreads();   // B1: sB ready

    // Phase 2: dense L2 + residual || cfconv groups 3-5
    if (hn) { IG(A, nb_, 3) IG(B, nb_, 4) }
    {
      f32x4 dacc[2];
      #pragma unroll
      for (int t = 0; t < 2; ++t) dacc[t] = (f32x4){bb2[t], bb2[t], bb2[t], bb2[t]};
      #pragma unroll
      for (int k0i = 0; k0i < 4; ++k0i) {
        const f16x8 af = AFRAGP(sB, k0i * 32);
        #pragma unroll
        for (int t = 0; t < 2; ++t)
          dacc[t] = __builtin_amdgcn_mfma_f32_16x16x32_f16(af, bw2[t][k0i], dacc[t], 0, 0, 0);
      }
      #pragma unroll
      for (int t = 0; t < 2; ++t) {
        const int c = w * 32 + t * 16 + rc;
        #pragma unroll
        for (int r = 0; r < 4; ++r) {
          const int mm = qk * 4 + r;
          const float x = embed[(size_t)sZb[b][mm] * 128 + c] + dacc[t][r];
          sX[swz(mm, c)] = (f16)x;
        }
      }
    }
    if (hn) { CG(A) IG(A, nb_, 5) CG(B) CG(A) }
    __syncthreads();   // B2: sX ready

    // Phase 3: MLP || cfconv groups 6-7 + agg write || stage chunk s+2
    if (hn) { IG(A, nb_, 6) IG(B, nb_, 7) }
    if (s + 2 < myChunks) STAGE(b, bid + (s + 2) * PBLOCKS)  // buffer b free since B3 of s-1
    {
      f32x4 a2 = (f32x4){bm, bm, bm, bm};
      #pragma unroll
      for (int k0i = 0; k0i < 4; ++k0i)
        a2 = __builtin_amdgcn_mfma_f32_16x16x32_f16(AFRAGP(sX, k0i * 32), bwm[k0i], a2, 0, 0, 0);
      #pragma unroll
      for (int r = 0; r < 4; ++r) vsum = fmaf(ssp(a2[r]), cm, vsum);
    }
    if (hn) { CG(A) CG(B) AGGW(nb_) }
    __syncthreads();   // B3: aggB[nb_] + s_pk[b] complete; sB/sX free
  }
#undef STAGE
#undef IG
#undef CG
#undef AGGW
#undef AFRAGP

  // ---- block reduce -> one atomicAdd per block ----
  #pragma unroll
  for (int o = 1; o < 64; o <<= 1) vsum += __shfl_xor(vsum, o, 64);
  if (l == 0) sRed[w] = vsum;
  __syncthreads();
  if (tid == 0) {
    atomicAdd(out, 20.0f * (sRed[0] + sRed[1] + sRed[2] + sRed[3]));
  }
}

extern "C" void kernel_launch(void* const* d_in, const int* in_sizes, int n_in,
                              void* d_out, int out_size, void* d_ws, size_t ws_size,
                              hipStream_t stream) {
  const float* dR    = (const float*)d_in[0];
  const int*   Z     = (const int*)  d_in[1];
  const int*   nbr   = (const int*)  d_in[2];
  const float* embed = (const float*)d_in[3];
  const float* fw1   = (const float*)d_in[4];
  const float* fb1   = (const float*)d_in[5];
  const float* fw2   = (const float*)d_in[6];
  const float* fb2   = (const float*)d_in[7];
  const float* in2f  = (const float*)d_in[8];
  const float* w1    = (const float*)d_in[9];
  const float* b1    = (const float*)d_in[10];
  const float* w2    = (const float*)d_in[11];
  const float* b2    = (const float*)d_in[12];
  const float* mw1   = (const float*)d_in[13];
  const float* mb1   = (const float*)d_in[14];
  const float* mw2   = (const float*)d_in[15];
  const float* mb2   = (const float*)d_in[16];
  float* out = (float*)d_out;

  char* ws = (char*)d_ws;
  f16*    tabh    = (f16*)ws;                               // 16 KB
  f16*    ytab    = (f16*)(ws + (size_t)64 * 1024);         // 25.6 KB
  f16*    w1ht    = (f16*)(ws + (size_t)128 * 1024);        // 32 KB
  f16*    w2ht    = (f16*)(ws + (size_t)192 * 1024);        // 32 KB
  f16*    mw1ht   = (f16*)(ws + (size_t)256 * 1024);        // 16 KB
  uint_t* pkAll   = (uint_t*)(ws + (size_t)1024 * 1024);    // 6.4 MB

  prep_all_kernel<<<NTB + 64 + PKB, 256, 0, stream>>>(fw1, fb1, fw2, fb2,
      w1, w2, mw1, embed, in2f, dR, nbr, Z, mb2,
      tabh, ytab, w1ht, w2ht, mw1ht, pkAll, out);
  fused_kernel<<<PBLOCKS, 256, 0, stream>>>(pkAll, Z, embed,
      tabh, ytab, w1ht, b1, w2ht, b2, mw1ht, mb1, mw2, out);
}

// Round 25
// 52.130 us; speedup vs baseline: 2.0026x; 1.0541x over previous
//
#include <hip/hip_runtime.h>
#include <math.h>

#define N_ATOMS  50000
#define N_NBRS   32
#define N_GAUSS  25
#define RCUT     5.0f
#define TT       192       // nearest-table nodes, spacing RCUT/191
#define TROWS    32
#define NTB      6         // 192/32 table-build blocks
#define MAXZ     100
#define NT32     1563      // ceil(50000/32) 32-atom chunks
#define PBLOCKS  256       // persistent fused blocks (1 per CU)
#define NPAIR    (N_ATOMS * N_NBRS)        // 1,600,000
#define PKPAD    (NT32 * 1024)             // 1,600,512 (padded)
#define PKB      782                       // pk-precompute blocks (2048 pairs each)
#define PI_F     3.14159265358979323846f

typedef unsigned int   uint_t;
typedef unsigned short ushort_t;
typedef _Float16 f16;
typedef f16   f16x2 __attribute__((ext_vector_type(2)));
typedef f16   f16x4 __attribute__((ext_vector_type(4)));
typedef f16   f16x8 __attribute__((ext_vector_type(8)));
typedef float f32x4 __attribute__((ext_vector_type(4)));

// fast shifted softplus: max(x,0) + log(0.5 + 0.5*exp(-|x|))
__device__ __forceinline__ float ssp(float x) {
  return fmaxf(x, 0.0f) + __logf(fmaf(0.5f, __expf(-fabsf(x)), 0.5f));
}
__device__ __forceinline__ f16x2 bch(uint_t u) {
  return __builtin_bit_cast(f16x2, u);
}
__device__ __forceinline__ uint_t hcb(f16x2 v) {
  return __builtin_bit_cast(uint_t, v);
}
// swizzled element offset into a [16][128] f16 LDS tile
__device__ __forceinline__ int swz(int m, int e) {
  return m * 128 + ((((e >> 3) ^ m) & 15) << 3) + (e & 7);
}

// ---- prep: [0,NTB) table; [NTB,NTB+64) transposes+ytab; [NTB+64,...) pair codes
__global__ void __launch_bounds__(256, 2)
prep_all_kernel(const float* __restrict__ fw1,
                const float* __restrict__ fb1,
                const float* __restrict__ fw2,
                const float* __restrict__ fb2,
                const float* __restrict__ w1,
                const float* __restrict__ w2,
                const float* __restrict__ mw1,
                const float* __restrict__ embed,
                const float* __restrict__ in2f,
                const float* __restrict__ dR,
                const int* __restrict__ nbr,
                const int* __restrict__ Z,
                const float* __restrict__ mb2,
                f16* __restrict__ tabh,
                f16* __restrict__ ytab,
                f16* __restrict__ w1ht,
                f16* __restrict__ w2ht,
                f16* __restrict__ mw1ht,
                uint_t* __restrict__ pkAll,
                float* __restrict__ out) {
  const int tid = threadIdx.x;
  const int bid = blockIdx.x;
  if (bid == 0 && tid == 0) {
    out[0] = 20.0f * (float)N_ATOMS * mb2[0];   // seed with bias term; fused adds the rest
  }

  __shared__ float sW2[128 * 128];       // 64 KB
  __shared__ float sH[TROWS][128];       // 16 KB

  if (bid >= NTB + 64) {
    // ---- pair-code precompute: pk = i0 | (Z[nbr] << 8) ----
    const int base = (bid - NTB - 64) * 2048;
    #pragma unroll
    for (int t0 = 0; t0 < 8; ++t0) {
      const int idx = base + t0 * 256 + tid;
      if (idx < PKPAD) {
        uint_t pk = 0;
        if (idx < NPAIR) {
          const float r = dR[idx];
          const int  nb = nbr[idx];
          int i0 = (int)(r * (191.0f / RCUT) + 0.5f);
          i0 = min(i0, 191);
          pk = (uint_t)i0 | ((uint_t)Z[nb] << 8);
        }
        pkAll[idx] = pk;
      }
    }
    return;
  }

  if (bid < NTB) {
    const int i0 = bid * TROWS;
    #pragma unroll
    for (int t = 0; t < 16; ++t) {
      const int e = tid + t * 256;
      ((float4*)sW2)[e] = ((const float4*)fw2)[e];
    }
    {
      const int f  = tid & 127;
      const int rh = (tid >> 7) * (TROWS / 2);
      const float delta = RCUT / (float)(N_GAUSS - 1);
      const float coeff = -0.5f / (delta * delta);
      const float b1v = fb1[f];
      for (int j = 0; j < TROWS / 2; ++j) {
        const float r = (float)(i0 + rh + j) * (RCUT / 191.0f);
        float h = b1v;
        #pragma unroll
        for (int g = 0; g < N_GAUSS; ++g) {
          const float d = r - (float)g * delta;
          h = fmaf(__expf(coeff * d * d), fw1[g * 128 + f], h);
        }
        sH[rh + j][f] = ssp(h);
      }
    }
    __syncthreads();
    {
      const int c0 = (tid & 31) * 4;
      const int rg = (tid >> 5) * 4;
      f32x4 acc[4];
      const float4 bv = *(const float4*)&fb2[c0];
      #pragma unroll
      for (int j = 0; j < 4; ++j) acc[j] = (f32x4){bv.x, bv.y, bv.z, bv.w};
      for (int k = 0; k < 128; ++k) {
        const float4 wv = *(const float4*)&sW2[k * 128 + c0];
        #pragma unroll
        for (int j = 0; j < 4; ++j) {
          const float hv = sH[rg + j][k];
          acc[j][0] = fmaf(hv, wv.x, acc[j][0]);
          acc[j][1] = fmaf(hv, wv.y, acc[j][1]);
          acc[j][2] = fmaf(hv, wv.z, acc[j][2]);
          acc[j][3] = fmaf(hv, wv.w, acc[j][3]);
        }
      }
      #pragma unroll
      for (int j = 0; j < 4; ++j) {
        const int i = i0 + rg + j;
        const float r = (float)i * (RCUT / 191.0f);
        const float fc = (r < RCUT) ? 0.5f * (__cosf(r * PI_F / RCUT) + 1.0f) : 0.0f;
        f16x4 o;
        #pragma unroll
        for (int c = 0; c < 4; ++c) o[c] = (f16)(acc[j][c] * fc);
        *(f16x4*)&tabh[i * 128 + c0] = o;
      }
    }
  } else {
    const int cc = (bid - NTB) * 2 + (tid >> 7);
    const int i  = tid & 127;
    w1ht[cc * 128 + i] = (f16)w1[i * 128 + cc];
    w2ht[cc * 128 + i] = (f16)w2[i * 128 + cc];
    if (cc < 64) mw1ht[cc * 128 + i] = (f16)mw1[i * 64 + cc];
    float* xs = &sH[0][0] + (tid >> 7) * 128;
    xs[i] = (cc < MAXZ) ? embed[cc * 128 + i] : 0.0f;
    __syncthreads();
    if (cc < MAXZ) {
      float acc = 0.0f;
      for (int j = 0; j < 128; j += 4) {
        const float4 xv = *reinterpret_cast<const float4*>(&xs[j]);
        acc = fmaf(xv.x, in2f[(j + 0) * 128 + i], acc);
        acc = fmaf(xv.y, in2f[(j + 1) * 128 + i], acc);
        acc = fmaf(xv.z, in2f[(j + 2) * 128 + i], acc);
        acc = fmaf(xv.w, in2f[(j + 3) * 128 + i], acc);
      }
      ytab[cc * 128 + i] = (f16)acc;
    }
  }
}

// ---- fused kernel: same-wave cross-chunk pipeline, precomputed pair codes,
//      3 barriers/chunk; finishes with ONE atomicAdd per block (no reduce kernel).
__global__ void __launch_bounds__(512, 2)
fused_kernel(const uint_t* __restrict__ pkAll,
             const int* __restrict__ Z,
             const float* __restrict__ embed,
             const f16* __restrict__ tabh,
             const f16* __restrict__ ytab,
             const f16* __restrict__ w1ht, const float* __restrict__ b1,
             const f16* __restrict__ w2ht, const float* __restrict__ b2,
             const f16* __restrict__ mw1ht, const float* __restrict__ mb1,
             const float* __restrict__ mw2,
             float* __restrict__ out) {
  const int tid = threadIdx.x;
  const int w   = tid >> 6;         // wave 0..7
  const int l   = tid & 63;
  const int q   = l >> 4;           // quarter
  const int cq  = l & 15;
  const int bid = blockIdx.x;

  __shared__ __align__(16) f16    sW[TT * 128];      // 48 KB nearest table
  __shared__ __align__(16) f16    sYT[MAXZ * 128];   // 25.6 KB y rows
  __shared__ __align__(16) uint_t s_pk[2][1024];     // 8 KB pair codes (dbuf)
  __shared__ __align__(16) f16    aggB[2][32 * 128]; // 16 KB agg (dbuf)
  __shared__ __align__(16) f16    sB[32 * 128];      // 8 KB h1
  __shared__ __align__(16) f16    sX[32 * 128];      // 8 KB xnew
  __shared__ int   sZb[2][32];
  __shared__ float sRed[8];

  for (int e = tid; e < TT * 16; e += 512)   ((uint4*)sW)[e]  = ((const uint4*)tabh)[e];
  for (int e = tid; e < MAXZ * 16; e += 512) ((uint4*)sYT)[e] = ((const uint4*)ytab)[e];

  // dense role indices
  const int g   = w >> 2;           // 16-atom tile within chunk
  const int wvg = w & 3;
  const int rc  = cq;
  const int qk  = q;
  f16x8 bw1[2][4], bw2[2][4], bwm[4];
  float bb1[2], bb2[2];
  #pragma unroll
  for (int t = 0; t < 2; ++t) {
    const int c = wvg * 32 + t * 16 + rc;
    bb1[t] = b1[c];
    bb2[t] = b2[c];
    #pragma unroll
    for (int k0i = 0; k0i < 4; ++k0i) {
      bw1[t][k0i] = *(const f16x8*)&w1ht[c * 128 + k0i * 32 + qk * 8];
      bw2[t][k0i] = *(const f16x8*)&w2ht[c * 128 + k0i * 32 + qk * 8];
    }
  }
  const int c1 = wvg * 16 + rc;
  #pragma unroll
  for (int k0i = 0; k0i < 4; ++k0i)
    bwm[k0i] = *(const f16x8*)&mw1ht[c1 * 128 + k0i * 32 + qk * 8];
  const float bm = mb1[c1];
  const float cm = mw2[c1];

  // cfconv role indices
  const int m = w * 4 + q;          // atom within 32-chunk
  const char* wb = (const char*)sW  + cq * 16;
  const char* yb = (const char*)sYT + cq * 16;

  const int myChunks = (NT32 - 1 - bid) / PBLOCKS + 1;
  float vsum = 0.0f;

  f16x2 acc[4];
  uint4 twA[4], ytA[4], twB[4], ytB[4];

#define STAGE(bb, cc) { \
    const uint2 v = *(const uint2*)&pkAll[(cc) * 1024 + tid * 2]; \
    *(uint2*)&s_pk[bb][tid * 2] = v; \
    if (tid < 32) sZb[bb][tid] = ((cc) * 32 + tid < N_ATOMS) ? Z[(cc) * 32 + tid] : 0; }

#define IG(BK, bb, gi) { \
    _Pragma("unroll") \
    for (int d = 0; d < 4; ++d) { \
      const uint_t pk = s_pk[bb][m * N_NBRS + (gi) * 4 + d]; \
      tw##BK[d] = *(const uint4*)(wb + ((pk & 0xFFu) << 8)); \
      yt##BK[d] = *(const uint4*)(yb + ((pk >> 8) << 8)); \
    } }

#define CG(BK) { \
    _Pragma("unroll") \
    for (int d = 0; d < 4; ++d) { \
      acc[0] += bch(tw##BK[d].x) * bch(yt##BK[d].x); \
      acc[1] += bch(tw##BK[d].y) * bch(yt##BK[d].y); \
      acc[2] += bch(tw##BK[d].z) * bch(yt##BK[d].z); \
      acc[3] += bch(tw##BK[d].w) * bch(yt##BK[d].w); \
    } }

#define AGGW(bb) { \
    uint4 o; \
    o.x = hcb(acc[0]); o.y = hcb(acc[1]); o.z = hcb(acc[2]); o.w = hcb(acc[3]); \
    const int mm = m & 15; \
    *(uint4*)&aggB[bb][(m >> 4) * 2048 + mm * 128 + (((cq ^ mm) & 15) << 3)] = o; }

#define AFRAGP(P, k0) (*(const f16x8*)&(P)[rc * 128 + (((((k0) >> 3) + qk) ^ rc) & 15) * 8])

  // ---- prologue: stage chunks 0 and 1, full cfconv for chunk 0 ----
  STAGE(0, bid)
  if (1 < myChunks) STAGE(1, bid + PBLOCKS)
  __syncthreads();     // tables + pk[0]/pk[1] visible
  #pragma unroll
  for (int c = 0; c < 4; ++c) acc[c] = (f16x2)0;
  IG(A, 0, 0) IG(B, 0, 1)
  CG(A) IG(A, 0, 2)
  CG(B) IG(B, 0, 3)
  CG(A) IG(A, 0, 4)
  CG(B) IG(B, 0, 5)
  CG(A) IG(A, 0, 6)
  CG(B) IG(B, 0, 7)
  CG(A)
  CG(B)
  AGGW(0)
  __syncthreads();     // aggB[0] ready

  // ---- main loop: 3 barriers per chunk ----
  for (int s = 0; s < myChunks; ++s) {
    const int b  = s & 1;
    const int cc = bid + s * PBLOCKS;
    const bool hn = (s + 1 < myChunks);
    const int nb_ = b ^ 1;

    if (hn) {
      #pragma unroll
      for (int c = 0; c < 4; ++c) acc[c] = (f16x2)0;
    }

    // Phase 1: dense L1 on aggB[b] || cfconv groups 0-2 of next chunk
    if (hn) { IG(A, nb_, 0) IG(B, nb_, 1) }
    {
      const f16* aggp = &aggB[b][g * 2048];
      f32x4 dacc[2];
      #pragma unroll
      for (int t = 0; t < 2; ++t) dacc[t] = (f32x4){bb1[t], bb1[t], bb1[t], bb1[t]};
      #pragma unroll
      for (int k0i = 0; k0i < 4; ++k0i) {
        const f16x8 af = AFRAGP(aggp, k0i * 32);
        #pragma unroll
        for (int t = 0; t < 2; ++t)
          dacc[t] = __builtin_amdgcn_mfma_f32_16x16x32_f16(af, bw1[t][k0i], dacc[t], 0, 0, 0);
      }
      f16* hB = &sB[g * 2048];
      #pragma unroll
      for (int t = 0; t < 2; ++t) {
        const int c = wvg * 32 + t * 16 + rc;
        #pragma unroll
        for (int r = 0; r < 4; ++r) hB[swz(qk * 4 + r, c)] = (f16)ssp(dacc[t][r]);
      }
    }
    if (hn) { CG(A) IG(A, nb_, 2) CG(B) CG(A) }
    __syncthreads();   // B1: sB ready

    // Phase 2: dense L2 + residual || cfconv groups 3-5
    if (hn) { IG(A, nb_, 3) IG(B, nb_, 4) }
    {
      const f16* hB = &sB[g * 2048];
      f16* hX = &sX[g * 2048];
      f32x4 dacc[2];
      #pragma unroll
      for (int t = 0; t < 2; ++t) dacc[t] = (f32x4){bb2[t], bb2[t], bb2[t], bb2[t]};
      #pragma unroll
      for (int k0i = 0; k0i < 4; ++k0i) {
        const f16x8 af = AFRAGP(hB, k0i * 32);
        #pragma unroll
        for (int t = 0; t < 2; ++t)
          dacc[t] = __builtin_amdgcn_mfma_f32_16x16x32_f16(af, bw2[t][k0i], dacc[t], 0, 0, 0);
      }
      #pragma unroll
      for (int t = 0; t < 2; ++t) {
        const int c = wvg * 32 + t * 16 + rc;
        #pragma unroll
        for (int r = 0; r < 4; ++r) {
          const int mm = qk * 4 + r;
          const float x = embed[(size_t)sZb[b][g * 16 + mm] * 128 + c] + dacc[t][r];
          hX[swz(mm, c)] = (f16)x;
        }
      }
    }
    if (hn) { CG(A) IG(A, nb_, 5) CG(B) CG(A) }
    __syncthreads();   // B2: sX ready

    // Phase 3: MLP || cfconv groups 6-7 + agg write || stage chunk s+2
    if (hn) { IG(A, nb_, 6) IG(B, nb_, 7) }
    if (s + 2 < myChunks) STAGE(b, bid + (s + 2) * PBLOCKS)  // buffer b free since B3 of s-1
    {
      const f16* hX = &sX[g * 2048];
      f32x4 a2 = (f32x4){bm, bm, bm, bm};
      #pragma unroll
      for (int k0i = 0; k0i < 4; ++k0i)
        a2 = __builtin_amdgcn_mfma_f32_16x16x32_f16(AFRAGP(hX, k0i * 32), bwm[k0i], a2, 0, 0, 0);
      #pragma unroll
      for (int r = 0; r < 4; ++r) {
        const int atom = cc * 32 + g * 16 + qk * 4 + r;
        if (atom < N_ATOMS) vsum = fmaf(ssp(a2[r]), cm, vsum);
      }
    }
    if (hn) { CG(A) CG(B) AGGW(nb_) }
    __syncthreads();   // B3: aggB[nb_] + s_pk[b] complete; sB/sX free
  }
#undef STAGE
#undef IG
#undef CG
#undef AGGW
#undef AFRAGP

  // ---- block reduce -> one atomicAdd per block ----
  #pragma unroll
  for (int o = 1; o < 64; o <<= 1) vsum += __shfl_xor(vsum, o, 64);
  if (l == 0) sRed[w] = vsum;
  __syncthreads();
  if (tid == 0) {
    float sF = 0.0f;
    #pragma unroll
    for (int i = 0; i < 8; ++i) sF += sRed[i];
    atomicAdd(out, 20.0f * sF);
  }
}

extern "C" void kernel_launch(void* const* d_in, const int* in_sizes, int n_in,
                              void* d_out, int out_size, void* d_ws, size_t ws_size,
                              hipStream_t stream) {
  const float* dR    = (const float*)d_in[0];
  const int*   Z     = (const int*)  d_in[1];
  const int*   nbr   = (const int*)  d_in[2];
  const float* embed = (const float*)d_in[3];
  const float* fw1   = (const float*)d_in[4];
  const float* fb1   = (const float*)d_in[5];
  const float* fw2   = (const float*)d_in[6];
  const float* fb2   = (const float*)d_in[7];
  const float* in2f  = (const float*)d_in[8];
  const float* w1    = (const float*)d_in[9];
  const float* b1    = (const float*)d_in[10];
  const float* w2    = (const float*)d_in[11];
  const float* b2    = (const float*)d_in[12];
  const float* mw1   = (const float*)d_in[13];
  const float* mb1   = (const float*)d_in[14];
  const float* mw2   = (const float*)d_in[15];
  const float* mb2   = (const float*)d_in[16];
  float* out = (float*)d_out;

  char* ws = (char*)d_ws;
  f16*    tabh    = (f16*)ws;                               // 48 KB
  f16*    ytab    = (f16*)(ws + (size_t)64 * 1024);         // 25.6 KB
  f16*    w1ht    = (f16*)(ws + (size_t)128 * 1024);        // 32 KB
  f16*    w2ht    = (f16*)(ws + (size_t)192 * 1024);        // 32 KB
  f16*    mw1ht   = (f16*)(ws + (size_t)256 * 1024);        // 16 KB
  uint_t* pkAll   = (uint_t*)(ws + (size_t)1024 * 1024);    // 6.4 MB

  prep_all_kernel<<<NTB + 64 + PKB, 256, 0, stream>>>(fw1, fb1, fw2, fb2,
      w1, w2, mw1, embed, in2f, dR, nbr, Z, mb2,
      tabh, ytab, w1ht, w2ht, mw1ht, pkAll, out);
  fused_kernel<<<PBLOCKS, 512, 0, stream>>>(pkAll, Z, embed,
      tabh, ytab, w1ht, b1, w2ht, b2, mw1ht, mb1, mw2, out);
}